// Round 2
// baseline (341.916 us; speedup 1.0000x reference)
//
#include <hip/hip_runtime.h>
#include <math.h>

// Shapes fixed by setup_inputs(): b=8, s=4096, h=16, p=64, n=64.
// out[b,h,p,n] = sum_t exp(Total(b,h) - P[t]) * X[b,t,h,p] * B[b,t,h,n],
// P = inclusive prefix sum of A over t (telescoped chunked scan; verified R1).

constexpr int Bn = 8;
constexpr int S  = 4096;
constexpr int H  = 16;
constexpr int Pp = 64;
constexpr int Nn = 64;
constexpr int SEG  = 128;      // prefix-sum granularity (t)
constexpr int NSEG = S / SEG;  // 32

// ---------- K1a: per-(bb,seg,h) segment sums of A (coalesced reads) ----------
__global__ __launch_bounds__(256) void seg_sums(const float* __restrict__ A,
                                                float* __restrict__ ss) {
  const int bb  = blockIdx.x >> 5;        // 8 batches
  const int seg = blockIdx.x & 31;        // 32 segments
  __shared__ float lds[SEG * H];          // 8 KB
  const float* src = A + ((size_t)bb * S + (size_t)seg * SEG) * H;
  const int tid = threadIdx.x;
  #pragma unroll
  for (int i = 0; i < 2; ++i)             // 2048 floats, coalesced float4
    ((float4*)lds)[tid + i * 256] = ((const float4*)src)[tid + i * 256];
  __syncthreads();
  if (tid < H) {                          // lane h: stride-16 reads, banks distinct
    float s = 0.f;
    for (int t = 0; t < SEG; ++t) s += lds[t * H + tid];
    ss[((size_t)bb * NSEG + seg) * H + tid] = s;
  }
}

// ---------- K1b: scan segment sums -> exclusive prefixes + totals ----------
__global__ __launch_bounds__(256) void seg_scan(const float* __restrict__ ss,
                                                float* __restrict__ pfx,
                                                float* __restrict__ tot) {
  const int pid = threadIdx.x;            // pair = bb*16 + h
  if (pid >= Bn * H) return;
  const int bb = pid >> 4, h = pid & 15;
  float run = 0.f;
  for (int s = 0; s < NSEG; ++s) {
    pfx[(size_t)pid * NSEG + s] = run;    // exclusive prefix at segment start
    run += ss[((size_t)bb * NSEG + s) * H + h];
  }
  tot[pid] = run;
}

// ---------- K2: barrier-free outer-product accumulation ----------
// Block = 4 waves, all on the same (pair, superchunk); wave w owns a disjoint
// 128-t range and a full 64x64 tile in registers (8x8 per lane). Fragments are
// loaded straight from global (8-lane broadcast groups hit L1). After the loop,
// a lane-major (conflict-free) LDS tree-reduce combines the 4 waves; wave 0
// stores one 16 KB block partial.
__global__ __launch_bounds__(256) void outer_k(const float* __restrict__ X,
                                               const float* __restrict__ Bm,
                                               const float* __restrict__ A,
                                               const float* __restrict__ pfx,
                                               const float* __restrict__ tot,
                                               float* __restrict__ part, int SC) {
  const int blk  = blockIdx.x;
  const int pair = blk / SC, sc = blk % SC;
  const int bb = pair >> 4, hh = pair & 15;
  const int tid = threadIdx.x, w = tid >> 6, lane = tid & 63;
  const int TPW = S / (SC * 4);           // t per wave (multiple of 128)
  const int t0  = sc * (S / SC) + w * TPW;
  const int r = lane >> 3, c = lane & 7;  // 8x8 lane grid; p0=r*8, n0=c*8

  float acc[8][8];
  #pragma unroll
  for (int i = 0; i < 8; ++i)
    #pragma unroll
    for (int j = 0; j < 8; ++j) acc[i][j] = 0.f;

  float run = pfx[(size_t)pair * NSEG + t0 / SEG];
  const float total = tot[pair];

  const float* Arow = A + ((size_t)bb * S + t0) * H + hh;
  const float* Xrow = X + (((size_t)bb * S + t0) * H + hh) * Pp + r * 8;
  const float* Brow = Bm + (((size_t)bb * S + t0) * H + hh) * Nn + c * 8;
  constexpr size_t TS = (size_t)H * Pp;   // 1024 floats per t step

  #pragma unroll 2
  for (int t = 0; t < TPW; ++t) {
    const float a = Arow[(size_t)t * H];
    run += a;                                       // inclusive P[t]
    const float wgt = __expf(total - run);          // <= 1 (A <= 0)
    const float4 x0 = *(const float4*)(Xrow + (size_t)t * TS);
    const float4 x1 = *(const float4*)(Xrow + (size_t)t * TS + 4);
    const float4 b0 = *(const float4*)(Brow + (size_t)t * TS);
    const float4 b1 = *(const float4*)(Brow + (size_t)t * TS + 4);
    const float xs[8] = {x0.x * wgt, x0.y * wgt, x0.z * wgt, x0.w * wgt,
                         x1.x * wgt, x1.y * wgt, x1.z * wgt, x1.w * wgt};
    const float bs[8] = {b0.x, b0.y, b0.z, b0.w, b1.x, b1.y, b1.z, b1.w};
    #pragma unroll
    for (int i = 0; i < 8; ++i)
      #pragma unroll
      for (int j = 0; j < 8; ++j)
        acc[i][j] = fmaf(xs[i], bs[j], acc[i][j]);
  }

  // cross-wave tree reduce; layout idx = (i*8+j)*64 + lane -> bank = lane&31
  __shared__ float red[2][4096];          // 32 KB
  if (w >= 2) {
    #pragma unroll
    for (int i = 0; i < 8; ++i)
      #pragma unroll
      for (int j = 0; j < 8; ++j) red[w - 2][(i * 8 + j) * 64 + lane] = acc[i][j];
  }
  __syncthreads();
  if (w < 2) {
    #pragma unroll
    for (int i = 0; i < 8; ++i)
      #pragma unroll
      for (int j = 0; j < 8; ++j) acc[i][j] += red[w][(i * 8 + j) * 64 + lane];
  }
  __syncthreads();
  if (w == 1) {
    #pragma unroll
    for (int i = 0; i < 8; ++i)
      #pragma unroll
      for (int j = 0; j < 8; ++j) red[0][(i * 8 + j) * 64 + lane] = acc[i][j];
  }
  __syncthreads();
  if (w == 0) {
    float* base = part + (size_t)blk * 4096;
    #pragma unroll
    for (int i = 0; i < 8; ++i) {
      #pragma unroll
      for (int j = 0; j < 8; ++j) acc[i][j] += red[0][(i * 8 + j) * 64 + lane];
      *(float4*)(base + (r * 8 + i) * 64 + c * 8)     =
          make_float4(acc[i][0], acc[i][1], acc[i][2], acc[i][3]);
      *(float4*)(base + (r * 8 + i) * 64 + c * 8 + 4) =
          make_float4(acc[i][4], acc[i][5], acc[i][6], acc[i][7]);
    }
  }
}

// ---------- K3: sum SC block partials per pair -> out ----------
__global__ __launch_bounds__(256) void reduce_k(const float* __restrict__ part,
                                                float* __restrict__ out, int SC) {
  const int idx  = blockIdx.x * 256 + threadIdx.x;  // float4 index
  const int pair = idx >> 10;                       // 1024 float4 per tile
  const int off  = (idx & 1023) * 4;
  float4 s = make_float4(0.f, 0.f, 0.f, 0.f);
  for (int sc = 0; sc < SC; ++sc) {
    const float4 v = *(const float4*)(part + ((size_t)(pair * SC + sc)) * 4096 + off);
    s.x += v.x; s.y += v.y; s.z += v.z; s.w += v.w;
  }
  *(float4*)(out + (size_t)pair * 4096 + off) = s;
}

extern "C" void kernel_launch(void* const* d_in, const int* in_sizes, int n_in,
                              void* d_out, int out_size, void* d_ws, size_t ws_size,
                              hipStream_t stream) {
  const float* X = (const float*)d_in[0];   // (b, s, h, p)
  const float* A = (const float*)d_in[1];   // (b, s, h)
  const float* B = (const float*)d_in[2];   // (b, s, h, n)
  float* out = (float*)d_out;               // (b, h, p, n)

  // pick superchunk count SC per pair to fit workspace
  int SC = 8;
  const size_t misc = (size_t)(Bn * NSEG * H + Bn * H * NSEG + Bn * H) * sizeof(float);
  while (SC > 1 && (size_t)Bn * H * SC * 4096 * sizeof(float) + misc > ws_size) SC >>= 1;

  float* part = (float*)d_ws;                               // 128*SC*16KB
  float* ss   = part + (size_t)Bn * H * SC * 4096;          // 4096 floats
  float* pfx  = ss + (size_t)Bn * NSEG * H;                 // 4096 floats
  float* tot  = pfx + (size_t)Bn * H * NSEG;                // 128 floats

  seg_sums<<<Bn * NSEG, 256, 0, stream>>>(A, ss);
  seg_scan<<<1, 256, 0, stream>>>(ss, pfx, tot);
  outer_k<<<Bn * H * SC, 256, 0, stream>>>(X, B, A, pfx, tot, part, SC);
  reduce_k<<<(Bn * H * Pp * Nn) / 4 / 256, 256, 0, stream>>>(part, out, SC);
}